// Round 1
// baseline (230.164 us; speedup 1.0000x reference)
//
#include <hip/hip_runtime.h>
#include <hip/hip_bf16.h>
#include <stdint.h>

#define R_ 8
#define N_ 8192
#define D_ 2048
#define A_ 128
#define J_ 1024          // R_*A_
#define LN_EPS 1e-5f

typedef __attribute__((ext_vector_type(8))) short bf16x8;   // 8 bf16 in 4 VGPRs
typedef __attribute__((ext_vector_type(4))) float f32x4;

__device__ inline ushort f2bf(float f) {
    union { float f; uint32_t u; } v; v.f = f;
    uint32_t u = v.u;
    return (ushort)((u + 0x7fffu + ((u >> 16) & 1u)) >> 16);   // RNE
}

// ---------------------------------------------------------------------------
// K1: per-row stats of x (shared by all routers), write xhat (bf16, ws) and
//     new_x[r] = xhat*ln_w[r] + ln_b[r] (fp32, 512 MiB -> memory bound)
// ---------------------------------------------------------------------------
__global__ __launch_bounds__(256) void k_ln_x(
    const float* __restrict__ x,
    const float* __restrict__ ln_w,
    const float* __restrict__ ln_b,
    float* __restrict__ new_x,
    ushort* __restrict__ xhat)
{
    __shared__ float sm[16];
    const int n = blockIdx.x;
    const int t = threadIdx.x;
    const float* xr = x + (size_t)n * D_;

    // two contiguous float4 segments per thread: d = t*4 and 1024 + t*4
    float4 v0 = *(const float4*)(xr + t * 4);
    float4 v1 = *(const float4*)(xr + 1024 + t * 4);
    float s  = v0.x + v0.y + v0.z + v0.w + v1.x + v1.y + v1.z + v1.w;
    float sq = v0.x*v0.x + v0.y*v0.y + v0.z*v0.z + v0.w*v0.w
             + v1.x*v1.x + v1.y*v1.y + v1.z*v1.z + v1.w*v1.w;
    #pragma unroll
    for (int o = 32; o > 0; o >>= 1) {
        s  += __shfl_xor(s,  o, 64);
        sq += __shfl_xor(sq, o, 64);
    }
    if ((t & 63) == 0) { sm[t >> 6] = s; sm[8 + (t >> 6)] = sq; }
    __syncthreads();
    s  = sm[0] + sm[1] + sm[2] + sm[3];
    sq = sm[8] + sm[9] + sm[10] + sm[11];
    const float mean = s * (1.0f / D_);
    const float var  = sq * (1.0f / D_) - mean * mean;
    const float rstd = rsqrtf(var + LN_EPS);

    float4 h0, h1;
    h0.x = (v0.x - mean) * rstd; h0.y = (v0.y - mean) * rstd;
    h0.z = (v0.z - mean) * rstd; h0.w = (v0.w - mean) * rstd;
    h1.x = (v1.x - mean) * rstd; h1.y = (v1.y - mean) * rstd;
    h1.z = (v1.z - mean) * rstd; h1.w = (v1.w - mean) * rstd;

    ushort4 p0 = make_ushort4(f2bf(h0.x), f2bf(h0.y), f2bf(h0.z), f2bf(h0.w));
    ushort4 p1 = make_ushort4(f2bf(h1.x), f2bf(h1.y), f2bf(h1.z), f2bf(h1.w));
    *(ushort4*)(xhat + (size_t)n * D_ + t * 4)        = p0;
    *(ushort4*)(xhat + (size_t)n * D_ + 1024 + t * 4) = p1;

    #pragma unroll
    for (int r = 0; r < R_; ++r) {
        const float* wr = ln_w + (size_t)r * D_;
        const float* br = ln_b + (size_t)r * D_;
        float4 w0 = *(const float4*)(wr + t * 4);
        float4 b0 = *(const float4*)(br + t * 4);
        float4 w1 = *(const float4*)(wr + 1024 + t * 4);
        float4 b1 = *(const float4*)(br + 1024 + t * 4);
        float4 o0, o1;
        o0.x = h0.x * w0.x + b0.x; o0.y = h0.y * w0.y + b0.y;
        o0.z = h0.z * w0.z + b0.z; o0.w = h0.w * w0.w + b0.w;
        o1.x = h1.x * w1.x + b1.x; o1.y = h1.y * w1.y + b1.y;
        o1.z = h1.z * w1.z + b1.z; o1.w = h1.w * w1.w + b1.w;
        float* dst = new_x + ((size_t)r * N_ + n) * D_;
        *(float4*)(dst + t * 4)        = o0;
        *(float4*)(dst + 1024 + t * 4) = o1;
    }
}

// ---------------------------------------------------------------------------
// K2: LayerNorm of W[r] columns over D; emit Bt[j][d] = bf16(ln_w[r,d]*rw_norm)
//     (B-transposed, K-major, for the MFMA GEMM) and c[j] = sum_d ln_b*rw_norm
//     + router_bias. j = r*128 + a.
// ---------------------------------------------------------------------------
__global__ __launch_bounds__(256) void k_wnorm(
    const float* __restrict__ W,
    const float* __restrict__ ln_w,
    const float* __restrict__ ln_b,
    const float* __restrict__ rw_w,
    const float* __restrict__ rw_b,
    const float* __restrict__ rbias,
    ushort* __restrict__ Bt,
    float* __restrict__ cvec)
{
    __shared__ float sm[16];
    const int j = blockIdx.x;
    const int r = j >> 7, a = j & 127;
    const int t = threadIdx.x;
    const float* Wc = W + (size_t)r * D_ * A_ + a;

    float vals[8];
    float s = 0.f, sq = 0.f;
    #pragma unroll
    for (int k = 0; k < 8; ++k) {
        float v = Wc[(size_t)(t + k * 256) * A_];
        vals[k] = v; s += v; sq += v * v;
    }
    #pragma unroll
    for (int o = 32; o > 0; o >>= 1) {
        s  += __shfl_xor(s,  o, 64);
        sq += __shfl_xor(sq, o, 64);
    }
    if ((t & 63) == 0) { sm[t >> 6] = s; sm[8 + (t >> 6)] = sq; }
    __syncthreads();
    s  = sm[0] + sm[1] + sm[2] + sm[3];
    sq = sm[8] + sm[9] + sm[10] + sm[11];
    const float mean = s * (1.0f / D_);
    const float var  = sq * (1.0f / D_) - mean * mean;
    const float rstd = rsqrtf(var + LN_EPS);

    float cp = 0.f;
    #pragma unroll
    for (int k = 0; k < 8; ++k) {
        const int d = t + k * 256;
        const float nv = (vals[k] - mean) * rstd * rw_w[(size_t)r * D_ + d]
                       + rw_b[(size_t)r * D_ + d];
        Bt[(size_t)j * D_ + d] = f2bf(ln_w[(size_t)r * D_ + d] * nv);
        cp += ln_b[(size_t)r * D_ + d] * nv;
    }
    __syncthreads();   // sm reuse
    #pragma unroll
    for (int o = 32; o > 0; o >>= 1) cp += __shfl_xor(cp, o, 64);
    if ((t & 63) == 0) sm[t >> 6] = cp;
    __syncthreads();
    if (t == 0) cvec[j] = sm[0] + sm[1] + sm[2] + sm[3] + rbias[(size_t)r * A_ + a];
}

// ---------------------------------------------------------------------------
// K3: GEMM logits[n][j] = sum_d xhat[n][d] * Bt[j][d] + c[j]
//     M=8192, J=1024, K=2048, bf16 MFMA 16x16x32, 128x128 tile, BK=32,
//     global_load_lds width-16 staging (m97 structure).
// ---------------------------------------------------------------------------
__global__ __launch_bounds__(256) void k_gemm(
    const ushort* __restrict__ Xh,
    const ushort* __restrict__ Bt,
    const float* __restrict__ cvec,
    float* __restrict__ logits)
{
    __shared__ __attribute__((aligned(16))) ushort As[128 * 32];
    __shared__ __attribute__((aligned(16))) ushort Bs[128 * 32];
    const int t    = threadIdx.x;
    const int lane = t & 63;
    const int w    = t >> 6;                 // wave 0..3, rows w*32..w*32+31
    const int m0   = blockIdx.x * 128;
    const int j0   = blockIdx.y * 128;

    f32x4 acc[2][8];
    #pragma unroll
    for (int mi = 0; mi < 2; ++mi)
        #pragma unroll
        for (int jf = 0; jf < 8; ++jf)
            acc[mi][jf] = (f32x4){0.f, 0.f, 0.f, 0.f};

    for (int kt = 0; kt < D_ / 32; ++kt) {
        __syncthreads();                     // previous iter's reads done
        #pragma unroll
        for (int c = 0; c < 2; ++c) {
            const int q   = t + c * 256;     // 16B chunk index 0..511
            const int row = q >> 2;          // 0..127
            const int kc  = q & 3;           // 16B sub-chunk within BK=32
            const ushort* gA = Xh + (size_t)(m0 + row) * D_ + kt * 32 + kc * 8;
            __builtin_amdgcn_global_load_lds(
                (const __attribute__((address_space(1))) void*)gA,
                (__attribute__((address_space(3))) void*)(&As[q * 8]), 16, 0, 0);
            const ushort* gB = Bt + (size_t)(j0 + row) * D_ + kt * 32 + kc * 8;
            __builtin_amdgcn_global_load_lds(
                (const __attribute__((address_space(1))) void*)gB,
                (__attribute__((address_space(3))) void*)(&Bs[q * 8]), 16, 0, 0);
        }
        __syncthreads();                     // drains vmcnt -> LDS ready

        bf16x8 afr[2];
        #pragma unroll
        for (int mi = 0; mi < 2; ++mi)
            afr[mi] = *(const bf16x8*)(&As[(w * 32 + mi * 16 + (lane & 15)) * 32
                                           + (lane >> 4) * 8]);
        #pragma unroll
        for (int jf = 0; jf < 8; ++jf) {
            bf16x8 bfr = *(const bf16x8*)(&Bs[(jf * 16 + (lane & 15)) * 32
                                              + (lane >> 4) * 8]);
            acc[0][jf] = __builtin_amdgcn_mfma_f32_16x16x32_bf16(afr[0], bfr, acc[0][jf], 0, 0, 0);
            acc[1][jf] = __builtin_amdgcn_mfma_f32_16x16x32_bf16(afr[1], bfr, acc[1][jf], 0, 0, 0);
        }
    }

    // epilogue: C/D layout col=lane&15, row=(lane>>4)*4+reg  [guide §3]
    const int r = j0 >> 7;                   // BN == A_, so j-tile == router
    #pragma unroll
    for (int mi = 0; mi < 2; ++mi) {
        #pragma unroll
        for (int jf = 0; jf < 8; ++jf) {
            const int aa   = jf * 16 + (lane & 15);
            const float ca = cvec[j0 + aa];
            #pragma unroll
            for (int reg = 0; reg < 4; ++reg) {
                const int row = m0 + w * 32 + mi * 16 + (lane >> 4) * 4 + reg;
                logits[((size_t)r * N_ + row) * A_ + aa] = acc[mi][jf][reg] + ca;
            }
        }
    }
}

// ---------------------------------------------------------------------------
// K4: softmax over A=128; one wave per (r,n) row, 4 rows per block.
// ---------------------------------------------------------------------------
__global__ __launch_bounds__(256) void k_softmax(
    const float* __restrict__ logits, float* __restrict__ probs)
{
    const int t = threadIdx.x;
    const size_t row = (size_t)blockIdx.x * 4 + (t >> 6);
    const int l = t & 63;
    const float* lg = logits + row * A_;
    const float v0 = lg[l], v1 = lg[l + 64];
    float mx = fmaxf(v0, v1);
    #pragma unroll
    for (int o = 32; o > 0; o >>= 1) mx = fmaxf(mx, __shfl_xor(mx, o, 64));
    const float e0 = __expf(v0 - mx), e1 = __expf(v1 - mx);
    float ssum = e0 + e1;
    #pragma unroll
    for (int o = 32; o > 0; o >>= 1) ssum += __shfl_xor(ssum, o, 64);
    const float inv = 1.0f / ssum;
    probs[row * A_ + l]      = e0 * inv;
    probs[row * A_ + l + 64] = e1 * inv;
}

// ---------------------------------------------------------------------------
extern "C" void kernel_launch(void* const* d_in, const int* in_sizes, int n_in,
                              void* d_out, int out_size, void* d_ws, size_t ws_size,
                              hipStream_t stream)
{
    const float* x     = (const float*)d_in[0];
    const float* ln_w  = (const float*)d_in[1];
    const float* ln_b  = (const float*)d_in[2];
    const float* W     = (const float*)d_in[3];
    const float* rw_w  = (const float*)d_in[4];
    const float* rw_b  = (const float*)d_in[5];
    const float* rbias = (const float*)d_in[6];

    float* out    = (float*)d_out;
    float* new_x  = out;                                   // [R,N,D]
    float* logits = out + (size_t)R_ * N_ * D_;            // [R,N,A]
    float* probs  = logits + (size_t)R_ * N_ * A_;         // [R,N,A]

    // ws: xhat bf16 [N][D] (32 MiB) | Bt bf16 [J][D] (4 MiB) | cvec f32 [J]
    ushort* xhat = (ushort*)d_ws;
    ushort* Btp  = (ushort*)((char*)d_ws + (size_t)N_ * D_ * 2);
    float*  cvec = (float*)((char*)d_ws + (size_t)N_ * D_ * 2 + (size_t)J_ * D_ * 2);

    hipLaunchKernelGGL(k_ln_x,    dim3(N_),             dim3(256), 0, stream,
                       x, ln_w, ln_b, new_x, xhat);
    hipLaunchKernelGGL(k_wnorm,   dim3(J_),             dim3(256), 0, stream,
                       W, ln_w, ln_b, rw_w, rw_b, rbias, Btp, cvec);
    hipLaunchKernelGGL(k_gemm,    dim3(N_ / 128, J_ / 128), dim3(256), 0, stream,
                       xhat, Btp, cvec, logits);
    hipLaunchKernelGGL(k_softmax, dim3(R_ * N_ / 4),    dim3(256), 0, stream,
                       logits, probs);
}

// Round 2
// 215.736 us; speedup vs baseline: 1.0669x; 1.0669x over previous
//
#include <hip/hip_runtime.h>
#include <hip/hip_bf16.h>
#include <stdint.h>

#define R_ 8
#define N_ 8192
#define D_ 2048
#define A_ 128
#define J_ 1024          // R_*A_
#define LN_EPS 1e-5f
#define GEMM_BLOCKS 512  // (N_/128) * (J_/128)

typedef __attribute__((ext_vector_type(8))) short bf16x8;   // 8 bf16 in 4 VGPRs
typedef __attribute__((ext_vector_type(4))) float f32x4;

__device__ inline ushort f2bf(float f) {
    union { float f; uint32_t u; } v; v.f = f;
    uint32_t u = v.u;
    return (ushort)((u + 0x7fffu + ((u >> 16) & 1u)) >> 16);   // RNE
}
__device__ inline float bf2f(ushort u) {
    union { uint32_t u; float f; } v; v.u = ((uint32_t)u) << 16;
    return v.f;
}

// ---------------------------------------------------------------------------
// k_prep: blocks [0,N_)   : row-LN stats of x -> xhat bf16 (shared by routers)
//         blocks [N_,N_+J_): weight-LN column j -> Bt bf16 (K-major) + cvec
// ---------------------------------------------------------------------------
__global__ __launch_bounds__(256) void k_prep(
    const float* __restrict__ x,
    const float* __restrict__ W,
    const float* __restrict__ ln_w,
    const float* __restrict__ ln_b,
    const float* __restrict__ rw_w,
    const float* __restrict__ rw_b,
    const float* __restrict__ rbias,
    ushort* __restrict__ xhat,
    ushort* __restrict__ Bt,
    float* __restrict__ cvec)
{
    __shared__ float sm[16];
    const int t = threadIdx.x;

    if (blockIdx.x < N_) {
        const int n = blockIdx.x;
        const float* xr = x + (size_t)n * D_;
        float4 v0 = *(const float4*)(xr + t * 4);
        float4 v1 = *(const float4*)(xr + 1024 + t * 4);
        float s  = v0.x + v0.y + v0.z + v0.w + v1.x + v1.y + v1.z + v1.w;
        float sq = v0.x*v0.x + v0.y*v0.y + v0.z*v0.z + v0.w*v0.w
                 + v1.x*v1.x + v1.y*v1.y + v1.z*v1.z + v1.w*v1.w;
        #pragma unroll
        for (int o = 32; o > 0; o >>= 1) {
            s  += __shfl_xor(s,  o, 64);
            sq += __shfl_xor(sq, o, 64);
        }
        if ((t & 63) == 0) { sm[t >> 6] = s; sm[8 + (t >> 6)] = sq; }
        __syncthreads();
        s  = sm[0] + sm[1] + sm[2] + sm[3];
        sq = sm[8] + sm[9] + sm[10] + sm[11];
        const float mean = s * (1.0f / D_);
        const float var  = sq * (1.0f / D_) - mean * mean;
        const float rstd = rsqrtf(var + LN_EPS);

        ushort4 p0 = make_ushort4(f2bf((v0.x - mean) * rstd), f2bf((v0.y - mean) * rstd),
                                  f2bf((v0.z - mean) * rstd), f2bf((v0.w - mean) * rstd));
        ushort4 p1 = make_ushort4(f2bf((v1.x - mean) * rstd), f2bf((v1.y - mean) * rstd),
                                  f2bf((v1.z - mean) * rstd), f2bf((v1.w - mean) * rstd));
        *(ushort4*)(xhat + (size_t)n * D_ + t * 4)        = p0;
        *(ushort4*)(xhat + (size_t)n * D_ + 1024 + t * 4) = p1;
    } else {
        const int j = blockIdx.x - N_;
        const int r = j >> 7, a = j & 127;
        const float* Wc = W + (size_t)r * D_ * A_ + a;

        float vals[8];
        float s = 0.f, sq = 0.f;
        #pragma unroll
        for (int k = 0; k < 8; ++k) {
            float v = Wc[(size_t)(t + k * 256) * A_];
            vals[k] = v; s += v; sq += v * v;
        }
        #pragma unroll
        for (int o = 32; o > 0; o >>= 1) {
            s  += __shfl_xor(s,  o, 64);
            sq += __shfl_xor(sq, o, 64);
        }
        if ((t & 63) == 0) { sm[t >> 6] = s; sm[8 + (t >> 6)] = sq; }
        __syncthreads();
        s  = sm[0] + sm[1] + sm[2] + sm[3];
        sq = sm[8] + sm[9] + sm[10] + sm[11];
        const float mean = s * (1.0f / D_);
        const float var  = sq * (1.0f / D_) - mean * mean;
        const float rstd = rsqrtf(var + LN_EPS);

        float cp = 0.f;
        #pragma unroll
        for (int k = 0; k < 8; ++k) {
            const int d = t + k * 256;
            const float nv = (vals[k] - mean) * rstd * rw_w[(size_t)r * D_ + d]
                           + rw_b[(size_t)r * D_ + d];
            Bt[(size_t)j * D_ + d] = f2bf(ln_w[(size_t)r * D_ + d] * nv);
            cp += ln_b[(size_t)r * D_ + d] * nv;
        }
        __syncthreads();   // sm reuse
        #pragma unroll
        for (int o = 32; o > 0; o >>= 1) cp += __shfl_xor(cp, o, 64);
        if ((t & 63) == 0) sm[t >> 6] = cp;
        __syncthreads();
        if (t == 0) cvec[j] = sm[0] + sm[1] + sm[2] + sm[3] + rbias[(size_t)r * A_ + a];
    }
}

// ---------------------------------------------------------------------------
// k_main: blocks [0,512)        : GEMM logits = xhat * Bt^T + c, fused softmax
//         blocks [512,512+N_)   : new_x[r][n] = f32(xhat[n]) * ln_w[r] + ln_b[r]
// Compute-bound GEMM overlaps the memory-bound 512 MiB new_x stream (m114:
// MFMA waves and mem waves co-schedule at ~max, not sum).
// ---------------------------------------------------------------------------
__global__ __launch_bounds__(256) void k_main(
    const ushort* __restrict__ Xh,
    const ushort* __restrict__ Bt,
    const float* __restrict__ cvec,
    const float* __restrict__ ln_w,
    const float* __restrict__ ln_b,
    float* __restrict__ new_x,
    float* __restrict__ logits,
    float* __restrict__ probs)
{
    __shared__ __attribute__((aligned(16))) ushort As[128 * 32];
    __shared__ __attribute__((aligned(16))) ushort Bs[128 * 32];
    const int t = threadIdx.x;

    if (blockIdx.x < GEMM_BLOCKS) {
        const int lane = t & 63;
        const int w    = t >> 6;                 // wave 0..3, rows w*32..+31
        const int m0   = (blockIdx.x >> 3) * 128;
        const int j0   = (blockIdx.x & 7) * 128;

        f32x4 acc[2][8];
        #pragma unroll
        for (int mi = 0; mi < 2; ++mi)
            #pragma unroll
            for (int jf = 0; jf < 8; ++jf)
                acc[mi][jf] = (f32x4){0.f, 0.f, 0.f, 0.f};

        for (int kt = 0; kt < D_ / 32; ++kt) {
            __syncthreads();                     // previous iter's reads done
            #pragma unroll
            for (int c = 0; c < 2; ++c) {
                const int q   = t + c * 256;     // 16B chunk index 0..511
                const int row = q >> 2;
                const int kc  = q & 3;
                const ushort* gA = Xh + (size_t)(m0 + row) * D_ + kt * 32 + kc * 8;
                __builtin_amdgcn_global_load_lds(
                    (const __attribute__((address_space(1))) void*)gA,
                    (__attribute__((address_space(3))) void*)(&As[q * 8]), 16, 0, 0);
                const ushort* gB = Bt + (size_t)(j0 + row) * D_ + kt * 32 + kc * 8;
                __builtin_amdgcn_global_load_lds(
                    (const __attribute__((address_space(1))) void*)gB,
                    (__attribute__((address_space(3))) void*)(&Bs[q * 8]), 16, 0, 0);
            }
            __syncthreads();                     // drains vmcnt -> LDS ready

            bf16x8 afr[2];
            #pragma unroll
            for (int mi = 0; mi < 2; ++mi)
                afr[mi] = *(const bf16x8*)(&As[(w * 32 + mi * 16 + (lane & 15)) * 32
                                               + (lane >> 4) * 8]);
            #pragma unroll
            for (int jf = 0; jf < 8; ++jf) {
                bf16x8 bfr = *(const bf16x8*)(&Bs[(jf * 16 + (lane & 15)) * 32
                                                  + (lane >> 4) * 8]);
                acc[0][jf] = __builtin_amdgcn_mfma_f32_16x16x32_bf16(afr[0], bfr, acc[0][jf], 0, 0, 0);
                acc[1][jf] = __builtin_amdgcn_mfma_f32_16x16x32_bf16(afr[1], bfr, acc[1][jf], 0, 0, 0);
            }
        }

        // Epilogue: bias add + row softmax (j-tile == one router's full A=128).
        // C/D layout: col = lane&15, row = (lane>>4)*4 + reg.
        const int r = j0 >> 7;
        float cv[8];
        #pragma unroll
        for (int jf = 0; jf < 8; ++jf) cv[jf] = cvec[j0 + jf * 16 + (lane & 15)];

        #pragma unroll
        for (int mi = 0; mi < 2; ++mi) {
            #pragma unroll
            for (int reg = 0; reg < 4; ++reg) {
                const int row = m0 + w * 32 + mi * 16 + (lane >> 4) * 4 + reg;
                float v[8], e[8];
                float mx = -3.4e38f;
                #pragma unroll
                for (int jf = 0; jf < 8; ++jf) {
                    v[jf] = acc[mi][jf][reg] + cv[jf];
                    mx = fmaxf(mx, v[jf]);
                }
                #pragma unroll
                for (int o = 8; o > 0; o >>= 1) mx = fmaxf(mx, __shfl_xor(mx, o, 64));
                float ssum = 0.f;
                #pragma unroll
                for (int jf = 0; jf < 8; ++jf) { e[jf] = __expf(v[jf] - mx); ssum += e[jf]; }
                #pragma unroll
                for (int o = 8; o > 0; o >>= 1) ssum += __shfl_xor(ssum, o, 64);
                const float inv = 1.0f / ssum;
                float* lrow = logits + ((size_t)r * N_ + row) * A_;
                float* prow = probs  + ((size_t)r * N_ + row) * A_;
                #pragma unroll
                for (int jf = 0; jf < 8; ++jf) {
                    const int aa = jf * 16 + (lane & 15);
                    lrow[aa] = v[jf];
                    prow[aa] = e[jf] * inv;
                }
            }
        }
    } else {
        // new_x writer: one block per input row n
        const int n = blockIdx.x - GEMM_BLOCKS;
        const ushort4 q0 = *(const ushort4*)(Xh + (size_t)n * D_ + t * 4);
        const ushort4 q1 = *(const ushort4*)(Xh + (size_t)n * D_ + 1024 + t * 4);
        const float h00 = bf2f(q0.x), h01 = bf2f(q0.y), h02 = bf2f(q0.z), h03 = bf2f(q0.w);
        const float h10 = bf2f(q1.x), h11 = bf2f(q1.y), h12 = bf2f(q1.z), h13 = bf2f(q1.w);

        #pragma unroll
        for (int r = 0; r < R_; ++r) {
            const float* wr = ln_w + (size_t)r * D_;
            const float* br = ln_b + (size_t)r * D_;
            float4 w0 = *(const float4*)(wr + t * 4);
            float4 b0 = *(const float4*)(br + t * 4);
            float4 w1 = *(const float4*)(wr + 1024 + t * 4);
            float4 b1 = *(const float4*)(br + 1024 + t * 4);
            float4 o0, o1;
            o0.x = h00 * w0.x + b0.x; o0.y = h01 * w0.y + b0.y;
            o0.z = h02 * w0.z + b0.z; o0.w = h03 * w0.w + b0.w;
            o1.x = h10 * w1.x + b1.x; o1.y = h11 * w1.y + b1.y;
            o1.z = h12 * w1.z + b1.z; o1.w = h13 * w1.w + b1.w;
            float* dst = new_x + ((size_t)r * N_ + n) * D_;
            *(float4*)(dst + t * 4)        = o0;
            *(float4*)(dst + 1024 + t * 4) = o1;
        }
    }
}

// ---------------------------------------------------------------------------
extern "C" void kernel_launch(void* const* d_in, const int* in_sizes, int n_in,
                              void* d_out, int out_size, void* d_ws, size_t ws_size,
                              hipStream_t stream)
{
    const float* x     = (const float*)d_in[0];
    const float* ln_w  = (const float*)d_in[1];
    const float* ln_b  = (const float*)d_in[2];
    const float* W     = (const float*)d_in[3];
    const float* rw_w  = (const float*)d_in[4];
    const float* rw_b  = (const float*)d_in[5];
    const float* rbias = (const float*)d_in[6];

    float* out    = (float*)d_out;
    float* new_x  = out;                                   // [R,N,D]
    float* logits = out + (size_t)R_ * N_ * D_;            // [R,N,A]
    float* probs  = logits + (size_t)R_ * N_ * A_;         // [R,N,A]

    // ws: xhat bf16 [N][D] (32 MiB) | Bt bf16 [J][D] (4 MiB) | cvec f32 [J]
    ushort* xhat = (ushort*)d_ws;
    ushort* Btp  = (ushort*)((char*)d_ws + (size_t)N_ * D_ * 2);
    float*  cvec = (float*)((char*)d_ws + (size_t)N_ * D_ * 2 + (size_t)J_ * D_ * 2);

    hipLaunchKernelGGL(k_prep, dim3(N_ + J_), dim3(256), 0, stream,
                       x, W, ln_w, ln_b, rw_w, rw_b, rbias, xhat, Btp, cvec);
    hipLaunchKernelGGL(k_main, dim3(GEMM_BLOCKS + N_), dim3(256), 0, stream,
                       xhat, Btp, cvec, ln_w, ln_b, new_x, logits, probs);
}